// Round 11
// baseline (305.832 us; speedup 1.0000x reference)
//
#include <hip/hip_runtime.h>
#include <hip/hip_bf16.h>

#define HID 64
#define NGRAPH 64
#define BSH 7            // bucket = 128 nodes
#define NCH 384          // edge chunks for hist/scatter

static inline size_t align256(size_t x) { return (x + 255) & ~(size_t)255; }

typedef __attribute__((ext_vector_type(8))) short bf16x8;
typedef __attribute__((ext_vector_type(4))) float f32x4;

// ---- dtype-agnostic float load: f32 ? fp32[i] : bf16[i] ----
__device__ __forceinline__ float ldf(const void* p, size_t i, int f32) {
    if (f32) return ((const float*)p)[i];
    unsigned int w = ((unsigned int)((const unsigned short*)p)[i]) << 16;
    return __uint_as_float(w);
}
__device__ __forceinline__ float bf2f(unsigned short u) {
    return __uint_as_float(((unsigned int)u) << 16);
}
__device__ __forceinline__ unsigned short f2bf(float f) {
    __hip_bfloat16 h = __float2bfloat16(f);
    return *(unsigned short*)&h;
}

// ---- fp8 e4m3fn encode/decode (OCP) ----
__device__ __forceinline__ unsigned char f2e4m3(float f) {
#if defined(__has_builtin) && __has_builtin(__builtin_amdgcn_cvt_pk_fp8_f32)
    int r = __builtin_amdgcn_cvt_pk_fp8_f32(f, f, 0, false);
    return (unsigned char)(r & 0xFF);
#else
    unsigned u = __float_as_uint(f);
    unsigned s = (u >> 24) & 0x80;
    unsigned a = u & 0x7FFFFFFF;
    float af = __uint_as_float(a);
    if (af < 0.015625f) {
        int m = (int)rintf(af * 512.f);
        return (unsigned char)(s | m);
    }
    unsigned r = a + 0x7FFFF + ((a >> 20) & 1);
    int e = (int)(r >> 23) - 127;
    if (e > 8) return (unsigned char)(s | 0x7E);
    return (unsigned char)(s | ((e + 7) << 3) | ((r >> 20) & 7));
#endif
}
template <int IDX>
__device__ __forceinline__ float d8(unsigned p) {
#if defined(__has_builtin) && __has_builtin(__builtin_amdgcn_cvt_f32_fp8)
    return __builtin_amdgcn_cvt_f32_fp8(p, IDX);
#else
    unsigned b = (p >> (IDX * 8)) & 0xFF;
    unsigned e = (b >> 3) & 0xF, m = b & 7;
    float v = e ? __uint_as_float(((e + 120) << 23) | (m << 20))
                : (float)m * (1.f / 512.f);
    return (b & 0x80) ? -v : v;
#endif
}

// ---------------- dtype sniffer + zero small accumulators ----------------
__global__ void k_sniff(const unsigned short* __restrict__ x, int nwords, int* __restrict__ flag,
                        float* __restrict__ gsum, int* __restrict__ gcnt) {
    __shared__ int cw, cz;
    int t = threadIdx.x;
    if (t == 0) { cw = 0; cz = 0; }
    if (t < NGRAPH) { gsum[t] = 0.f; gcnt[t] = 0; }
    __syncthreads();
    int weird = 0, evenzero = 0;
    for (int i = t; i < nwords; i += blockDim.x) {
        unsigned short u = x[i];
        int e = (u >> 7) & 0xFF;
        if (e >= 128) weird++;
        if (((i & 1) == 0) && ((u & 0x7FFF) == 0)) evenzero++;
    }
    atomicAdd(&cw, weird);
    atomicAdd(&cz, evenzero);
    __syncthreads();
    if (t == 0) *flag = (cw > nwords / 16 || cz > nwords / 8) ? 1 : 0;
}

// ---------------- merged prep: gcnt + pack + hist ----------------
__global__ __launch_bounds__(256) void k_prep(const int* __restrict__ batch, int* __restrict__ gcnt,
                                              int n, int nbG,
                                              const void* W0, const void* RW0, const void* b0, const void* rb0,
                                              const void* W1, const void* RW1, const void* b1, const void* rb1,
                                              const void* W2, const void* RW2, const void* b2, const void* rb2,
                                              const int* __restrict__ dflag,
                                              unsigned short* wt0, unsigned short* wt1, unsigned short* wt2,
                                              float* bcat,
                                              const int* __restrict__ ecol, int e, int nbuck,
                                              int* __restrict__ hist) {
    __shared__ int sh[1024];
    int b = blockIdx.x, t = threadIdx.x;
    if (b < nbG) {
        if (t < NGRAPH) sh[t] = 0;
        __syncthreads();
        int i = b * 256 + t;
        if (i < n) atomicAdd(&sh[batch[i]], 1);
        __syncthreads();
        if (t < NGRAPH && sh[t] > 0) atomicAdd(&gcnt[t], sh[t]);
    } else if (b < nbG + 130) {
        int f = *dflag;
        int i = (b - nbG) * 256 + t;
        if (i < 16384) {
            int nn = i >> 7, k = i & 127;
            float v = (nn < 64) ? ldf(W0, (size_t)k * 64 + nn, f) : ldf(RW0, (size_t)k * 64 + (nn - 64), f);
            wt0[nn * 128 + k] = f2bf(v);
        } else if (i < 24576) {
            int j = i - 16384; int nn = j >> 6, k = j & 63;
            float v = (nn < 64) ? ldf(W1, (size_t)k * 64 + nn, f) : ldf(RW1, (size_t)k * 64 + (nn - 64), f);
            wt1[nn * 64 + k] = f2bf(v);
        } else if (i < 32768) {
            int j = i - 24576; int nn = j >> 6, k = j & 63;
            float v = (nn < 64) ? ldf(W2, (size_t)k * 64 + nn, f) : ldf(RW2, (size_t)k * 64 + (nn - 64), f);
            wt2[nn * 64 + k] = f2bf(v);
        } else if (i < 32768 + 192) {
            int j = i - 32768; int l = j >> 6, c = j & 63;
            const void* bb = (l == 0) ? b0 : (l == 1) ? b1 : b2;
            const void* rr = (l == 0) ? rb0 : (l == 1) ? rb1 : rb2;
            bcat[l * 64 + c] = ldf(bb, c, f) + ldf(rr, c, f);
        }
    } else {
        int c = b - nbG - 130;
        for (int i = t; i < nbuck; i += 256) sh[i] = 0;
        __syncthreads();
        int per = (e + NCH - 1) / NCH;
        int s = c * per, en = min(e, s + per);
        for (int i = s + t; i < en; i += 256)
            atomicAdd(&sh[ecol[i] >> BSH], 1);
        __syncthreads();
        for (int i = t; i < nbuck; i += 256) hist[i * NCH + c] = sh[i];
    }
}

// ---------------- hierarchical scan ----------------
__global__ void k_scan1(const int* __restrict__ src, int* __restrict__ bsum, int n) {
    __shared__ int s[256];
    int t = threadIdx.x;
    int base = blockIdx.x * 1024 + t * 4;
    int sum = 0;
#pragma unroll
    for (int j = 0; j < 4; j++) { int i = base + j; if (i < n) sum += src[i]; }
    s[t] = sum;
    __syncthreads();
    for (int o = 128; o > 0; o >>= 1) {
        if (t < o) s[t] += s[t + o];
        __syncthreads();
    }
    if (t == 0) bsum[blockIdx.x] = s[0];
}

__global__ void k_scan2(const int* __restrict__ bsum, int* __restrict__ bscan,
                        int* __restrict__ out, int nb, int n) {
    __shared__ int s[256];
    int t = threadIdx.x;
    int v = (t < nb) ? bsum[t] : 0;
    s[t] = v;
    __syncthreads();
    for (int o = 1; o < 256; o <<= 1) {
        int x = (t >= o) ? s[t - o] : 0;
        __syncthreads();
        s[t] += x;
        __syncthreads();
    }
    if (t < nb) bscan[t] = s[t] - v;
    if (t == nb - 1) out[n] = s[t];
}

__global__ void k_scan3(const int* __restrict__ src, const int* __restrict__ bscan,
                        int* __restrict__ out, int n) {
    __shared__ int s[256];
    int t = threadIdx.x;
    int base = blockIdx.x * 1024 + t * 4;
    int tsum = 0;
#pragma unroll
    for (int j = 0; j < 4; j++) { int i = base + j; if (i < n) tsum += src[i]; }
    s[t] = tsum;
    __syncthreads();
    for (int o = 1; o < 256; o <<= 1) {
        int x = (t >= o) ? s[t - o] : 0;
        __syncthreads();
        s[t] += x;
        __syncthreads();
    }
    int off = bscan[blockIdx.x] + s[t] - tsum;
#pragma unroll
    for (int j = 0; j < 4; j++) {
        int i = base + j;
        if (i < n) { out[i] = off; off += src[i]; }
    }
}

// ---------------- bucket scatter: esrc[pos]=src, et7[pos]=tgt&127 ----------------
__global__ __launch_bounds__(512) void k_scatter(const int* __restrict__ erow,
                                                 const int* __restrict__ ecol, int e, int nbuck,
                                                 const int* __restrict__ hoffs,
                                                 int* __restrict__ esrc,
                                                 unsigned char* __restrict__ et7) {
    __shared__ int cur[1024];
    int c = blockIdx.x, t = threadIdx.x;
    for (int i = t; i < nbuck; i += 512) cur[i] = hoffs[i * NCH + c];
    __syncthreads();
    int per = (e + NCH - 1) / NCH;
    int s = c * per, en = min(e, s + per);
    for (int i = s + t; i < en; i += 512) {
        int tg = ecol[i];
        int p = atomicAdd(&cur[tg >> BSH], 1);
        esrc[p] = erow[i];
        et7[p] = (unsigned char)(tg & 127);
    }
}

// ---------------- per-bucket: degree hist + local scan -> offs/dis + CSR fill ----------------
__global__ __launch_bounds__(256) void k_bucket(const int* __restrict__ esrc,
                                                const unsigned char* __restrict__ et7,
                                                const int* __restrict__ hoffs,
                                                int nbuck, int n, int e,
                                                int* __restrict__ offs, float* __restrict__ dis,
                                                int* __restrict__ csr) {
    __shared__ int hist[128];
    __shared__ int lofs[128];
    __shared__ int curs[128];
    int b = blockIdx.x, t = threadIdx.x;
    int nb0 = b << BSH;
    int nn = n - nb0; if (nn > 128) nn = 128;
    int s = hoffs[b * NCH];
    int en = (b + 1 < nbuck) ? hoffs[(b + 1) * NCH] : e;
    if (t < 128) hist[t] = 0;
    __syncthreads();
    for (int i = s + t; i < en; i += 256)
        atomicAdd(&hist[et7[i]], 1);
    __syncthreads();
    if (t < 128) lofs[t] = hist[t];
    __syncthreads();
    for (int o = 1; o < 128; o <<= 1) {
        int v = (t < 128 && t >= o) ? lofs[t - o] : 0;
        __syncthreads();
        if (t < 128) lofs[t] += v;
        __syncthreads();
    }
    if (t < nn) {
        int ex = s + lofs[t] - hist[t];
        offs[nb0 + t] = ex;
        curs[t] = ex;
        dis[nb0 + t] = rsqrtf((float)(hist[t] + 1));
    }
    if (b == nbuck - 1 && t == 0) offs[n] = e;
    __syncthreads();
    for (int i = s + t; i < en; i += 256) {
        int p = atomicAdd(&curs[et7[i]], 1);
        csr[p] = esrc[i];
    }
}

// ---------------- MFMA dual GEMM; B-operand from global (L1/L2-hot), hs out fp8 ----------------
template <int K, bool XFLAG, bool LO>
__global__ __launch_bounds__(256) void k_gemm(const void* __restrict__ xin,
                                              const unsigned short* __restrict__ wt,
                                              const float* __restrict__ bcat,
                                              const float* __restrict__ dis,
                                              const int* __restrict__ dflag,
                                              unsigned char* __restrict__ hs,
                                              float* __restrict__ base, int n) {
    const int KP = K + 8;
    __shared__ unsigned short sXh[64 * KP];
    __shared__ unsigned short sXl[LO ? 64 * KP : 1];
    int f32 = *dflag;
    int tid = threadIdx.x;
    int row0 = blockIdx.x * 64;

    if (XFLAG && !f32) {
        const uint4* xv = (const uint4*)xin;
        const int C = K / 8;
        for (int i = tid; i < 64 * C; i += 256) {
            int r = i / C, c = i % C;
            int gr = row0 + r;
            uint4 v = (gr < n) ? xv[(size_t)gr * C + c] : make_uint4(0, 0, 0, 0);
            *(uint4*)&sXh[r * KP + c * 8] = v;
        }
    } else if (XFLAG) {
        for (int i = tid; i < 64 * K; i += 256) {
            int r = i / K, k = i - r * K;
            int gr = row0 + r;
            float v = (gr < n) ? ((const float*)xin)[(size_t)gr * K + k] : 0.f;
            sXh[r * KP + k] = f2bf(v);
        }
    } else {
        const float4* xv = (const float4*)xin;
        const int C = K / 4;
        for (int i = tid; i < 64 * C; i += 256) {
            int r = i / C, c = i % C;
            int gr = row0 + r;
            float4 v = (gr < n) ? xv[(size_t)gr * C + c] : make_float4(0.f, 0.f, 0.f, 0.f);
            ushort4 h, lo;
            h.x = f2bf(v.x); h.y = f2bf(v.y); h.z = f2bf(v.z); h.w = f2bf(v.w);
            if (LO) {
                lo.x = f2bf(v.x - bf2f(h.x)); lo.y = f2bf(v.y - bf2f(h.y));
                lo.z = f2bf(v.z - bf2f(h.z)); lo.w = f2bf(v.w - bf2f(h.w));
            }
            *(ushort4*)&sXh[r * KP + c * 4] = h;
            if (LO) *(ushort4*)&sXl[r * KP + c * 4] = lo;
        }
    }
    __syncthreads();

    int w = tid >> 6, lane = tid & 63;
    int m = lane & 15, q = lane >> 4;
    f32x4 acc[8];
#pragma unroll
    for (int ct = 0; ct < 8; ct++) acc[ct] = (f32x4){0.f, 0.f, 0.f, 0.f};

    int arow = w * 16 + m;
#pragma unroll
    for (int ks = 0; ks < K / 32; ks++) {
        int ka = ks * 32 + q * 8;
        bf16x8 ah = *(const bf16x8*)&sXh[arow * KP + ka];
        bf16x8 al;
        if (LO) al = *(const bf16x8*)&sXl[arow * KP + ka];
#pragma unroll
        for (int ct = 0; ct < 8; ct++) {
            bf16x8 bb = *(const bf16x8*)(wt + (size_t)(ct * 16 + m) * K + ka);
            acc[ct] = __builtin_amdgcn_mfma_f32_16x16x32_bf16(ah, bb, acc[ct], 0, 0, 0);
            if (LO) acc[ct] = __builtin_amdgcn_mfma_f32_16x16x32_bf16(al, bb, acc[ct], 0, 0, 0);
        }
    }

#pragma unroll
    for (int ct = 0; ct < 4; ct++) {
        int col = ct * 16 + m;
#pragma unroll
        for (int reg = 0; reg < 4; reg++) {
            int r = row0 + w * 16 + q * 4 + reg;
            if (r < n) {
                float dv = dis[r];
                float h = acc[ct][reg] * dv;
                hs[(size_t)r * 64 + col] = f2e4m3(h);
                base[(size_t)r * 64 + col] = h * dv + acc[ct + 4][reg] + bcat[col];
            }
        }
    }
}

// ---------------- gather-aggregate + LN (+relu / +readout) ----------------
// 16-lane group per node; coalesced csr chunk load, shfl-broadcast indices,
// full-16 gather batch when the chunk is full (16 loads in flight/group).
template <bool FINAL>
__global__ __launch_bounds__(1024) void k_agg_ln(const unsigned char* __restrict__ hs,
                                                 const float* __restrict__ base,
                                                 const float* __restrict__ dis,
                                                 const int* __restrict__ offs,
                                                 const int* __restrict__ csr,
                                                 const void* __restrict__ gam,
                                                 const void* __restrict__ bet,
                                                 const int* __restrict__ dflag,
                                                 float* __restrict__ xout, int n, int relu,
                                                 const int* __restrict__ batch,
                                                 const void* __restrict__ lw,
                                                 float* __restrict__ gsum) {
    __shared__ float sG[FINAL ? NGRAPH : 1];
    int f32 = *dflag;
    int t = threadIdx.x;
    if (FINAL) {
        if (t < NGRAPH) sG[t] = 0.f;
        __syncthreads();
    }
    int grp = t >> 4;
    int l = t & 15;
    int gl0 = (t & 63) & ~15;
    int v = blockIdx.x * 64 + grp;
    if (v < n) {
        int s = offs[v];
        int e2 = offs[v + 1];
        float4 bv = *(const float4*)&base[(size_t)v * 64 + l * 4];
        float dv = dis[v];
        float a0 = 0.f, a1 = 0.f, a2 = 0.f, a3 = 0.f;
        for (int gbase = s; gbase < e2; gbase += 16) {
            int cnt = e2 - gbase; if (cnt > 16) cnt = 16;
            int cur = (gbase + l < e2) ? csr[gbase + l] : 0;
            if (cnt == 16) {
                unsigned pp[16];
#pragma unroll
                for (int j = 0; j < 16; j++) {
                    int sj = __shfl(cur, gl0 + j, 64);
                    pp[j] = *(const unsigned*)(hs + (size_t)sj * 64 + l * 4);
                }
#pragma unroll
                for (int j = 0; j < 16; j++) {
                    a0 += d8<0>(pp[j]);
                    a1 += d8<1>(pp[j]);
                    a2 += d8<2>(pp[j]);
                    a3 += d8<3>(pp[j]);
                }
            } else {
                int j = 0;
                for (; j + 7 < cnt; j += 8) {
                    unsigned pp[8];
#pragma unroll
                    for (int u = 0; u < 8; u++) {
                        int sj = __shfl(cur, gl0 + j + u, 64);
                        pp[u] = *(const unsigned*)(hs + (size_t)sj * 64 + l * 4);
                    }
#pragma unroll
                    for (int u = 0; u < 8; u++) {
                        a0 += d8<0>(pp[u]);
                        a1 += d8<1>(pp[u]);
                        a2 += d8<2>(pp[u]);
                        a3 += d8<3>(pp[u]);
                    }
                }
                for (; j + 3 < cnt; j += 4) {
                    unsigned pp[4];
#pragma unroll
                    for (int u = 0; u < 4; u++) {
                        int sj = __shfl(cur, gl0 + j + u, 64);
                        pp[u] = *(const unsigned*)(hs + (size_t)sj * 64 + l * 4);
                    }
#pragma unroll
                    for (int u = 0; u < 4; u++) {
                        a0 += d8<0>(pp[u]);
                        a1 += d8<1>(pp[u]);
                        a2 += d8<2>(pp[u]);
                        a3 += d8<3>(pp[u]);
                    }
                }
                for (; j < cnt; j++) {
                    int sj = __shfl(cur, gl0 + j, 64);
                    unsigned p0 = *(const unsigned*)(hs + (size_t)sj * 64 + l * 4);
                    a0 += d8<0>(p0);
                    a1 += d8<1>(p0);
                    a2 += d8<2>(p0);
                    a3 += d8<3>(p0);
                }
            }
        }
        a0 = bv.x + dv * a0;
        a1 = bv.y + dv * a1;
        a2 = bv.z + dv * a2;
        a3 = bv.w + dv * a3;
        float m = a0 + a1 + a2 + a3;
        m += __shfl_xor(m, 1, 64); m += __shfl_xor(m, 2, 64);
        m += __shfl_xor(m, 4, 64); m += __shfl_xor(m, 8, 64);
        m *= (1.f / 64.f);
        float d0 = a0 - m, d1 = a1 - m, d2 = a2 - m, d3 = a3 - m;
        float var = d0 * d0 + d1 * d1 + d2 * d2 + d3 * d3;
        var += __shfl_xor(var, 1, 64); var += __shfl_xor(var, 2, 64);
        var += __shfl_xor(var, 4, 64); var += __shfl_xor(var, 8, 64);
        var *= (1.f / 64.f);
        float rs = rsqrtf(var + 1e-5f);
        float y0 = d0 * rs * ldf(gam, l * 4 + 0, f32) + ldf(bet, l * 4 + 0, f32);
        float y1 = d1 * rs * ldf(gam, l * 4 + 1, f32) + ldf(bet, l * 4 + 1, f32);
        float y2 = d2 * rs * ldf(gam, l * 4 + 2, f32) + ldf(bet, l * 4 + 2, f32);
        float y3 = d3 * rs * ldf(gam, l * 4 + 3, f32) + ldf(bet, l * 4 + 3, f32);
        if (relu) {
            y0 = fmaxf(y0, 0.f); y1 = fmaxf(y1, 0.f);
            y2 = fmaxf(y2, 0.f); y3 = fmaxf(y3, 0.f);
        }
        if (!FINAL) {
            *(float4*)&xout[(size_t)v * 64 + l * 4] = make_float4(y0, y1, y2, y3);
        } else {
            float val = y0 * ldf(lw, l * 4 + 0, f32) + y1 * ldf(lw, l * 4 + 1, f32)
                      + y2 * ldf(lw, l * 4 + 2, f32) + y3 * ldf(lw, l * 4 + 3, f32);
            val += __shfl_xor(val, 1, 64); val += __shfl_xor(val, 2, 64);
            val += __shfl_xor(val, 4, 64); val += __shfl_xor(val, 8, 64);
            if (l == 0) atomicAdd(&sG[batch[v]], val);
        }
    }
    if (FINAL) {
        __syncthreads();
        if (t < NGRAPH && sG[t] != 0.f) atomicAdd(&gsum[t], sG[t]);
    }
}

// ---------------- finalize ----------------
__global__ void k_final(const float* __restrict__ gsum, const int* __restrict__ gcnt,
                        const void* __restrict__ lb, const int* __restrict__ dflag,
                        void* __restrict__ out, int g) {
    int f32 = *dflag;
    int i = threadIdx.x;
    if (i < g) {
        float c = fmaxf((float)gcnt[i], 1.f);
        float v = gsum[i] / c + ldf(lb, 0, f32);
        if (f32) ((float*)out)[i] = v;
        else ((__hip_bfloat16*)out)[i] = __float2bfloat16(v);
    }
}

extern "C" void kernel_launch(void* const* d_in, const int* in_sizes, int n_in,
                              void* d_out, int out_size, void* d_ws, size_t ws_size,
                              hipStream_t stream) {
    const void* x_in = d_in[0];
    const int* edge_index = (const int*)d_in[1];
    const int* batch = (const int*)d_in[2];
    const void *W0 = d_in[3], *b0 = d_in[4], *W1 = d_in[5], *b1 = d_in[6],
               *W2 = d_in[7], *b2 = d_in[8];
    const void *RW0 = d_in[9], *rb0 = d_in[10], *RW1 = d_in[11], *rb1 = d_in[12],
               *RW2 = d_in[13], *rb2 = d_in[14];
    const void *g0 = d_in[15], *be0 = d_in[16], *g1 = d_in[17], *be1 = d_in[18],
               *g2 = d_in[19], *be2 = d_in[20], *lw = d_in[21], *lb = d_in[22];

    const int N = in_sizes[2];
    const int E = in_sizes[1] / 2;
    const int* erow = edge_index;
    const int* ecol = edge_index + E;
    const int nbuck = (N + 127) >> BSH;
    const int T = nbuck * NCH;

    // workspace carve
    char* p = (char*)d_ws;
    size_t off = 0;
    float* dis = (float*)(p + off);  off = align256(off + (size_t)N * 4);
    int* offs = (int*)(p + off);     off = align256(off + (size_t)(N + 1) * 4);
    int* csr = (int*)(p + off);      off = align256(off + (size_t)E * 4);
    int* esrc = (int*)(p + off);     off = align256(off + (size_t)E * 4);
    unsigned char* et7 = (unsigned char*)(p + off); off = align256(off + (size_t)E);
    int* hist = (int*)(p + off);     off = align256(off + (size_t)T * 4);
    int* hoffs = (int*)(p + off);    off = align256(off + (size_t)(T + 1) * 4);
    unsigned char* hs = (unsigned char*)(p + off); off = align256(off + (size_t)N * HID);
    float* base = (float*)(p + off); off = align256(off + (size_t)N * HID * 4);
    float* xbuf = (float*)(p + off); off = align256(off + (size_t)N * HID * 4);
    unsigned short* wt0 = (unsigned short*)(p + off); off = align256(off + 16384 * 2);
    unsigned short* wt1 = (unsigned short*)(p + off); off = align256(off + 8192 * 2);
    unsigned short* wt2 = (unsigned short*)(p + off); off = align256(off + 8192 * 2);
    float* bcat = (float*)(p + off); off = align256(off + 192 * 4);
    int* bsum = (int*)(p + off);     off = align256(off + 256 * 4);
    int* bscan = (int*)(p + off);    off = align256(off + 256 * 4);
    float* gsum = (float*)(p + off); off = align256(off + NGRAPH * 4);
    int* gcnt = (int*)(p + off);     off = align256(off + NGRAPH * 4);
    int* dflag = (int*)(p + off);    off = align256(off + 4);
    (void)ws_size;

    const int TB = 256;
    int nbG = (N + TB - 1) / TB;
    int nbT = (T + 1023) / 1024;
    int nb_gemm = (N + 63) / 64;
    int nb_agg = (N + 63) / 64;

    k_sniff<<<1, 256, 0, stream>>>((const unsigned short*)x_in, 8192, dflag, gsum, gcnt);
    k_prep<<<nbG + 130 + NCH, TB, 0, stream>>>(batch, gcnt, N, nbG,
                                               W0, RW0, b0, rb0, W1, RW1, b1, rb1,
                                               W2, RW2, b2, rb2, dflag, wt0, wt1, wt2, bcat,
                                               ecol, E, nbuck, hist);
    k_scan1<<<nbT, TB, 0, stream>>>(hist, bsum, T);
    k_scan2<<<1, TB, 0, stream>>>(bsum, bscan, hoffs, nbT, T);
    k_scan3<<<nbT, TB, 0, stream>>>(hist, bscan, hoffs, T);
    k_scatter<<<NCH, 512, 0, stream>>>(erow, ecol, E, nbuck, hoffs, esrc, et7);
    k_bucket<<<nbuck, TB, 0, stream>>>(esrc, et7, hoffs, nbuck, N, E, offs, dis, csr);

    // layer 0 (K=128, x dtype per flag)
    k_gemm<128, true, false><<<nb_gemm, TB, 0, stream>>>(x_in, wt0, bcat, dis, dflag, hs, base, N);
    k_agg_ln<false><<<nb_agg, 1024, 0, stream>>>(hs, base, dis, offs, csr, g0, be0, dflag,
                                                 xbuf, N, 1, nullptr, nullptr, nullptr);
    // layer 1 (K=64, fp32 x, hi/lo split)
    k_gemm<64, false, true><<<nb_gemm, TB, 0, stream>>>(xbuf, wt1, bcat + 64, dis, dflag, hs, base, N);
    k_agg_ln<false><<<nb_agg, 1024, 0, stream>>>(hs, base, dis, offs, csr, g1, be1, dflag,
                                                 xbuf, N, 1, nullptr, nullptr, nullptr);
    // layer 2 (no relu, fused readout)
    k_gemm<64, false, true><<<nb_gemm, TB, 0, stream>>>(xbuf, wt2, bcat + 128, dis, dflag, hs, base, N);
    k_agg_ln<true><<<nb_agg, 1024, 0, stream>>>(hs, base, dis, offs, csr, g2, be2, dflag,
                                                nullptr, N, 0, batch, lw, gsum);

    k_final<<<1, 64, 0, stream>>>(gsum, gcnt, lb, dflag, d_out, NGRAPH);
}

// Round 12
// 267.570 us; speedup vs baseline: 1.1430x; 1.1430x over previous
//
#include <hip/hip_runtime.h>
#include <hip/hip_bf16.h>

#define HID 64
#define NGRAPH 64
#define BSH 7            // bucket = 128 nodes
#define NCH 384          // edge chunks for hist/scatter

static inline size_t align256(size_t x) { return (x + 255) & ~(size_t)255; }

typedef __attribute__((ext_vector_type(8))) short bf16x8;
typedef __attribute__((ext_vector_type(4))) float f32x4;

// ---- dtype-agnostic float load: f32 ? fp32[i] : bf16[i] ----
__device__ __forceinline__ float ldf(const void* p, size_t i, int f32) {
    if (f32) return ((const float*)p)[i];
    unsigned int w = ((unsigned int)((const unsigned short*)p)[i]) << 16;
    return __uint_as_float(w);
}
__device__ __forceinline__ float bf2f(unsigned short u) {
    return __uint_as_float(((unsigned int)u) << 16);
}
__device__ __forceinline__ unsigned short f2bf(float f) {
    __hip_bfloat16 h = __float2bfloat16(f);
    return *(unsigned short*)&h;
}

// ---- fp8 e4m3fn encode/decode (OCP) ----
__device__ __forceinline__ unsigned char f2e4m3(float f) {
#if defined(__has_builtin) && __has_builtin(__builtin_amdgcn_cvt_pk_fp8_f32)
    int r = __builtin_amdgcn_cvt_pk_fp8_f32(f, f, 0, false);
    return (unsigned char)(r & 0xFF);
#else
    unsigned u = __float_as_uint(f);
    unsigned s = (u >> 24) & 0x80;
    unsigned a = u & 0x7FFFFFFF;
    float af = __uint_as_float(a);
    if (af < 0.015625f) {
        int m = (int)rintf(af * 512.f);
        return (unsigned char)(s | m);
    }
    unsigned r = a + 0x7FFFF + ((a >> 20) & 1);
    int e = (int)(r >> 23) - 127;
    if (e > 8) return (unsigned char)(s | 0x7E);
    return (unsigned char)(s | ((e + 7) << 3) | ((r >> 20) & 7));
#endif
}
template <int IDX>
__device__ __forceinline__ float d8(unsigned p) {
#if defined(__has_builtin) && __has_builtin(__builtin_amdgcn_cvt_f32_fp8)
    return __builtin_amdgcn_cvt_f32_fp8(p, IDX);
#else
    unsigned b = (p >> (IDX * 8)) & 0xFF;
    unsigned e = (b >> 3) & 0xF, m = b & 7;
    float v = e ? __uint_as_float(((e + 120) << 23) | (m << 20))
                : (float)m * (1.f / 512.f);
    return (b & 0x80) ? -v : v;
#endif
}

// ---------------- dtype sniffer + zero small accumulators ----------------
__global__ void k_sniff(const unsigned short* __restrict__ x, int nwords, int* __restrict__ flag,
                        float* __restrict__ gsum, int* __restrict__ gcnt) {
    __shared__ int cw, cz;
    int t = threadIdx.x;
    if (t == 0) { cw = 0; cz = 0; }
    if (t < NGRAPH) { gsum[t] = 0.f; gcnt[t] = 0; }
    __syncthreads();
    int weird = 0, evenzero = 0;
    for (int i = t; i < nwords; i += blockDim.x) {
        unsigned short u = x[i];
        int e = (u >> 7) & 0xFF;
        if (e >= 128) weird++;
        if (((i & 1) == 0) && ((u & 0x7FFF) == 0)) evenzero++;
    }
    atomicAdd(&cw, weird);
    atomicAdd(&cz, evenzero);
    __syncthreads();
    if (t == 0) *flag = (cw > nwords / 16 || cz > nwords / 8) ? 1 : 0;
}

// ---------------- merged prep: gcnt + pack + hist ----------------
__global__ __launch_bounds__(256) void k_prep(const int* __restrict__ batch, int* __restrict__ gcnt,
                                              int n, int nbG,
                                              const void* W0, const void* RW0, const void* b0, const void* rb0,
                                              const void* W1, const void* RW1, const void* b1, const void* rb1,
                                              const void* W2, const void* RW2, const void* b2, const void* rb2,
                                              const int* __restrict__ dflag,
                                              unsigned short* wt0, unsigned short* wt1, unsigned short* wt2,
                                              float* bcat,
                                              const int* __restrict__ ecol, int e, int nbuck,
                                              int* __restrict__ hist) {
    __shared__ int sh[1024];
    int b = blockIdx.x, t = threadIdx.x;
    if (b < nbG) {
        if (t < NGRAPH) sh[t] = 0;
        __syncthreads();
        int i = b * 256 + t;
        if (i < n) atomicAdd(&sh[batch[i]], 1);
        __syncthreads();
        if (t < NGRAPH && sh[t] > 0) atomicAdd(&gcnt[t], sh[t]);
    } else if (b < nbG + 130) {
        int f = *dflag;
        int i = (b - nbG) * 256 + t;
        if (i < 16384) {
            int nn = i >> 7, k = i & 127;
            float v = (nn < 64) ? ldf(W0, (size_t)k * 64 + nn, f) : ldf(RW0, (size_t)k * 64 + (nn - 64), f);
            wt0[nn * 128 + k] = f2bf(v);
        } else if (i < 24576) {
            int j = i - 16384; int nn = j >> 6, k = j & 63;
            float v = (nn < 64) ? ldf(W1, (size_t)k * 64 + nn, f) : ldf(RW1, (size_t)k * 64 + (nn - 64), f);
            wt1[nn * 64 + k] = f2bf(v);
        } else if (i < 32768) {
            int j = i - 24576; int nn = j >> 6, k = j & 63;
            float v = (nn < 64) ? ldf(W2, (size_t)k * 64 + nn, f) : ldf(RW2, (size_t)k * 64 + (nn - 64), f);
            wt2[nn * 64 + k] = f2bf(v);
        } else if (i < 32768 + 192) {
            int j = i - 32768; int l = j >> 6, c = j & 63;
            const void* bb = (l == 0) ? b0 : (l == 1) ? b1 : b2;
            const void* rr = (l == 0) ? rb0 : (l == 1) ? rb1 : rb2;
            bcat[l * 64 + c] = ldf(bb, c, f) + ldf(rr, c, f);
        }
    } else {
        int c = b - nbG - 130;
        for (int i = t; i < nbuck; i += 256) sh[i] = 0;
        __syncthreads();
        int per = (e + NCH - 1) / NCH;
        int s = c * per, en = min(e, s + per);
        for (int i = s + t; i < en; i += 256)
            atomicAdd(&sh[ecol[i] >> BSH], 1);
        __syncthreads();
        for (int i = t; i < nbuck; i += 256) hist[i * NCH + c] = sh[i];
    }
}

// ---------------- hierarchical scan ----------------
__global__ void k_scan1(const int* __restrict__ src, int* __restrict__ bsum, int n) {
    __shared__ int s[256];
    int t = threadIdx.x;
    int base = blockIdx.x * 1024 + t * 4;
    int sum = 0;
#pragma unroll
    for (int j = 0; j < 4; j++) { int i = base + j; if (i < n) sum += src[i]; }
    s[t] = sum;
    __syncthreads();
    for (int o = 128; o > 0; o >>= 1) {
        if (t < o) s[t] += s[t + o];
        __syncthreads();
    }
    if (t == 0) bsum[blockIdx.x] = s[0];
}

__global__ void k_scan2(const int* __restrict__ bsum, int* __restrict__ bscan,
                        int* __restrict__ out, int nb, int n) {
    __shared__ int s[256];
    int t = threadIdx.x;
    int v = (t < nb) ? bsum[t] : 0;
    s[t] = v;
    __syncthreads();
    for (int o = 1; o < 256; o <<= 1) {
        int x = (t >= o) ? s[t - o] : 0;
        __syncthreads();
        s[t] += x;
        __syncthreads();
    }
    if (t < nb) bscan[t] = s[t] - v;
    if (t == nb - 1) out[n] = s[t];
}

__global__ void k_scan3(const int* __restrict__ src, const int* __restrict__ bscan,
                        int* __restrict__ out, int n) {
    __shared__ int s[256];
    int t = threadIdx.x;
    int base = blockIdx.x * 1024 + t * 4;
    int tsum = 0;
#pragma unroll
    for (int j = 0; j < 4; j++) { int i = base + j; if (i < n) tsum += src[i]; }
    s[t] = tsum;
    __syncthreads();
    for (int o = 1; o < 256; o <<= 1) {
        int x = (t >= o) ? s[t - o] : 0;
        __syncthreads();
        s[t] += x;
        __syncthreads();
    }
    int off = bscan[blockIdx.x] + s[t] - tsum;
#pragma unroll
    for (int j = 0; j < 4; j++) {
        int i = base + j;
        if (i < n) { out[i] = off; off += src[i]; }
    }
}

// ---------------- bucket scatter: esrc[pos]=src, et7[pos]=tgt&127 ----------------
__global__ __launch_bounds__(256) void k_scatter(const int* __restrict__ erow,
                                                 const int* __restrict__ ecol, int e, int nbuck,
                                                 const int* __restrict__ hoffs,
                                                 int* __restrict__ esrc,
                                                 unsigned char* __restrict__ et7) {
    __shared__ int cur[1024];
    int c = blockIdx.x, t = threadIdx.x;
    for (int i = t; i < nbuck; i += 256) cur[i] = hoffs[i * NCH + c];
    __syncthreads();
    int per = (e + NCH - 1) / NCH;
    int s = c * per, en = min(e, s + per);
    for (int i = s + t; i < en; i += 256) {
        int tg = ecol[i];
        int p = atomicAdd(&cur[tg >> BSH], 1);
        esrc[p] = erow[i];
        et7[p] = (unsigned char)(tg & 127);
    }
}

// ---------------- per-bucket: degree hist + local scan -> offs/dis + CSR fill ----------------
__global__ __launch_bounds__(256) void k_bucket(const int* __restrict__ esrc,
                                                const unsigned char* __restrict__ et7,
                                                const int* __restrict__ hoffs,
                                                int nbuck, int n, int e,
                                                int* __restrict__ offs, float* __restrict__ dis,
                                                int* __restrict__ csr) {
    __shared__ int hist[128];
    __shared__ int lofs[128];
    __shared__ int curs[128];
    int b = blockIdx.x, t = threadIdx.x;
    int nb0 = b << BSH;
    int nn = n - nb0; if (nn > 128) nn = 128;
    int s = hoffs[b * NCH];
    int en = (b + 1 < nbuck) ? hoffs[(b + 1) * NCH] : e;
    if (t < 128) hist[t] = 0;
    __syncthreads();
    for (int i = s + t; i < en; i += 256)
        atomicAdd(&hist[et7[i]], 1);
    __syncthreads();
    if (t < 128) lofs[t] = hist[t];
    __syncthreads();
    for (int o = 1; o < 128; o <<= 1) {
        int v = (t < 128 && t >= o) ? lofs[t - o] : 0;
        __syncthreads();
        if (t < 128) lofs[t] += v;
        __syncthreads();
    }
    if (t < nn) {
        int ex = s + lofs[t] - hist[t];
        offs[nb0 + t] = ex;
        curs[t] = ex;
        dis[nb0 + t] = rsqrtf((float)(hist[t] + 1));
    }
    if (b == nbuck - 1 && t == 0) offs[n] = e;
    __syncthreads();
    for (int i = s + t; i < en; i += 256) {
        int p = atomicAdd(&curs[et7[i]], 1);
        csr[p] = esrc[i];
    }
}

// ---------------- MFMA dual GEMM (layer 0 only; round-9 proven: sW staged in LDS) ----------------
template <int K, bool XFLAG, bool LO>
__global__ __launch_bounds__(256) void k_gemm(const void* __restrict__ xin,
                                              const unsigned short* __restrict__ wt,
                                              const float* __restrict__ bcat,
                                              const float* __restrict__ dis,
                                              const int* __restrict__ dflag,
                                              unsigned char* __restrict__ hs,
                                              float* __restrict__ base, int n) {
    const int KP = K + 8;
    __shared__ unsigned short sXh[64 * KP];
    __shared__ unsigned short sXl[LO ? 64 * KP : 1];
    __shared__ unsigned short sW[128 * KP];
    int f32 = *dflag;
    int tid = threadIdx.x;
    int row0 = blockIdx.x * 64;

    {   // stage packed weights as uint4, row-remapped for pad
        const uint4* src = (const uint4*)wt;
        uint4* dst = (uint4*)sW;
        const int C = K / 8;
        const int CP = KP / 8;
        for (int i = tid; i < 128 * C; i += 256) {
            int nrow = i / C, c = i % C;
            dst[nrow * CP + c] = src[i];
        }
    }
    if (XFLAG && !f32) {
        const uint4* xv = (const uint4*)xin;
        const int C = K / 8;
        for (int i = tid; i < 64 * C; i += 256) {
            int r = i / C, c = i % C;
            int gr = row0 + r;
            uint4 v = (gr < n) ? xv[(size_t)gr * C + c] : make_uint4(0, 0, 0, 0);
            *(uint4*)&sXh[r * KP + c * 8] = v;
        }
    } else if (XFLAG) {
        for (int i = tid; i < 64 * K; i += 256) {
            int r = i / K, k = i - r * K;
            int gr = row0 + r;
            float v = (gr < n) ? ((const float*)xin)[(size_t)gr * K + k] : 0.f;
            sXh[r * KP + k] = f2bf(v);
        }
    } else {
        const float4* xv = (const float4*)xin;
        const int C = K / 4;
        for (int i = tid; i < 64 * C; i += 256) {
            int r = i / C, c = i % C;
            int gr = row0 + r;
            float4 v = (gr < n) ? xv[(size_t)gr * C + c] : make_float4(0.f, 0.f, 0.f, 0.f);
            ushort4 h, lo;
            h.x = f2bf(v.x); h.y = f2bf(v.y); h.z = f2bf(v.z); h.w = f2bf(v.w);
            if (LO) {
                lo.x = f2bf(v.x - bf2f(h.x)); lo.y = f2bf(v.y - bf2f(h.y));
                lo.z = f2bf(v.z - bf2f(h.z)); lo.w = f2bf(v.w - bf2f(h.w));
            }
            *(ushort4*)&sXh[r * KP + c * 4] = h;
            if (LO) *(ushort4*)&sXl[r * KP + c * 4] = lo;
        }
    }
    __syncthreads();

    int w = tid >> 6, lane = tid & 63;
    int m = lane & 15, q = lane >> 4;
    f32x4 acc[8];
#pragma unroll
    for (int ct = 0; ct < 8; ct++) acc[ct] = (f32x4){0.f, 0.f, 0.f, 0.f};

    int arow = w * 16 + m;
#pragma unroll
    for (int ks = 0; ks < K / 32; ks++) {
        int ka = ks * 32 + q * 8;
        bf16x8 ah = *(const bf16x8*)&sXh[arow * KP + ka];
        bf16x8 al;
        if (LO) al = *(const bf16x8*)&sXl[arow * KP + ka];
#pragma unroll
        for (int ct = 0; ct < 8; ct++) {
            bf16x8 bb = *(const bf16x8*)&sW[(ct * 16 + m) * KP + ka];
            acc[ct] = __builtin_amdgcn_mfma_f32_16x16x32_bf16(ah, bb, acc[ct], 0, 0, 0);
            if (LO) acc[ct] = __builtin_amdgcn_mfma_f32_16x16x32_bf16(al, bb, acc[ct], 0, 0, 0);
        }
    }

#pragma unroll
    for (int ct = 0; ct < 4; ct++) {
        int col = ct * 16 + m;
#pragma unroll
        for (int reg = 0; reg < 4; reg++) {
            int r = row0 + w * 16 + q * 4 + reg;
            if (r < n) {
                float dv = dis[r];
                float h = acc[ct][reg] * dv;
                hs[(size_t)r * 64 + col] = f2e4m3(h);
                base[(size_t)r * 64 + col] = h * dv + acc[ct + 4][reg] + bcat[col];
            }
        }
    }
}

// ---------------- fused: gather-agg + LN + [next-layer dual GEMM | readout] ----------------
// 1024 threads, 64 nodes/block, 16-lane group per node (round-9 agg structure).
// GN: after LN, y (hi/lo bf16) -> LDS; 16 waves run the 64x128x64 dual GEMM
// (wave = row-tile rt=ww&3, col-pair c2=ww>>2 covering W-tile c2 + RW-tile c2+4),
// writing hs/base for the next layer. Double-buffered hs/base avoids RAW races.
template <bool GN>
__global__ __launch_bounds__(1024) void k_fagg(const unsigned char* __restrict__ hs_in,
                                               const float* __restrict__ base_in,
                                               const float* __restrict__ dis,
                                               const int* __restrict__ offs,
                                               const int* __restrict__ csr,
                                               const void* __restrict__ gam,
                                               const void* __restrict__ bet,
                                               const int* __restrict__ dflag,
                                               int n, int relu,
                                               const unsigned short* __restrict__ wt,
                                               const float* __restrict__ bcat,
                                               unsigned char* __restrict__ hs_out,
                                               float* __restrict__ base_out,
                                               const int* __restrict__ batch,
                                               const void* __restrict__ lw,
                                               float* __restrict__ gsum) {
    __shared__ unsigned short sYh[GN ? 64 * 72 : 1];
    __shared__ unsigned short sYl[GN ? 64 * 72 : 1];
    __shared__ unsigned short sW[GN ? 128 * 72 : 1];
    __shared__ float sG[GN ? 1 : NGRAPH];
    int t = threadIdx.x;
    int f32 = *dflag;
    if (GN) {
        // stage wt (128 rows x 64 k, bf16) -> sW rows padded to 72 shorts (1 uint4/thread)
        const uint4* src = (const uint4*)wt;
        uint4* dst = (uint4*)sW;
        int nrow = t >> 3, c = t & 7;
        dst[nrow * 9 + c] = src[t];
    } else {
        if (t < NGRAPH) sG[t] = 0.f;
        __syncthreads();
    }

    int grp = t >> 4;
    int l = t & 15;
    int gl0 = (t & 63) & ~15;
    int row0 = blockIdx.x * 64;
    int v = row0 + grp;
    float y0 = 0.f, y1 = 0.f, y2 = 0.f, y3 = 0.f;
    if (v < n) {
        int s = offs[v];
        int e2 = offs[v + 1];
        float4 bv = *(const float4*)&base_in[(size_t)v * 64 + l * 4];
        float dv = dis[v];
        float a0 = 0.f, a1 = 0.f, a2 = 0.f, a3 = 0.f;
        for (int gbase = s; gbase < e2; gbase += 16) {
            int cnt = e2 - gbase; if (cnt > 16) cnt = 16;
            int cur = (gbase + l < e2) ? csr[gbase + l] : 0;
            int j = 0;
            for (; j + 7 < cnt; j += 8) {
                unsigned pp[8];
#pragma unroll
                for (int u = 0; u < 8; u++) {
                    int sj = __shfl(cur, gl0 + j + u, 64);
                    pp[u] = *(const unsigned*)(hs_in + (size_t)sj * 64 + l * 4);
                }
#pragma unroll
                for (int u = 0; u < 8; u++) {
                    a0 += d8<0>(pp[u]);
                    a1 += d8<1>(pp[u]);
                    a2 += d8<2>(pp[u]);
                    a3 += d8<3>(pp[u]);
                }
            }
            for (; j + 3 < cnt; j += 4) {
                unsigned pp[4];
#pragma unroll
                for (int u = 0; u < 4; u++) {
                    int sj = __shfl(cur, gl0 + j + u, 64);
                    pp[u] = *(const unsigned*)(hs_in + (size_t)sj * 64 + l * 4);
                }
#pragma unroll
                for (int u = 0; u < 4; u++) {
                    a0 += d8<0>(pp[u]);
                    a1 += d8<1>(pp[u]);
                    a2 += d8<2>(pp[u]);
                    a3 += d8<3>(pp[u]);
                }
            }
            for (; j < cnt; j++) {
                int sj = __shfl(cur, gl0 + j, 64);
                unsigned p0 = *(const unsigned*)(hs_in + (size_t)sj * 64 + l * 4);
                a0 += d8<0>(p0);
                a1 += d8<1>(p0);
                a2 += d8<2>(p0);
                a3 += d8<3>(p0);
            }
        }
        a0 = bv.x + dv * a0;
        a1 = bv.y + dv * a1;
        a2 = bv.z + dv * a2;
        a3 = bv.w + dv * a3;
        float m = a0 + a1 + a2 + a3;
        m += __shfl_xor(m, 1, 64); m += __shfl_xor(m, 2, 64);
        m += __shfl_xor(m, 4, 64); m += __shfl_xor(m, 8, 64);
        m *= (1.f / 64.f);
        float d0 = a0 - m, d1 = a1 - m, d2 = a2 - m, d3 = a3 - m;
        float var = d0 * d0 + d1 * d1 + d2 * d2 + d3 * d3;
        var += __shfl_xor(var, 1, 64); var += __shfl_xor(var, 2, 64);
        var += __shfl_xor(var, 4, 64); var += __shfl_xor(var, 8, 64);
        var *= (1.f / 64.f);
        float rs = rsqrtf(var + 1e-5f);
        y0 = d0 * rs * ldf(gam, l * 4 + 0, f32) + ldf(bet, l * 4 + 0, f32);
        y1 = d1 * rs * ldf(gam, l * 4 + 1, f32) + ldf(bet, l * 4 + 1, f32);
        y2 = d2 * rs * ldf(gam, l * 4 + 2, f32) + ldf(bet, l * 4 + 2, f32);
        y3 = d3 * rs * ldf(gam, l * 4 + 3, f32) + ldf(bet, l * 4 + 3, f32);
        if (relu) {
            y0 = fmaxf(y0, 0.f); y1 = fmaxf(y1, 0.f);
            y2 = fmaxf(y2, 0.f); y3 = fmaxf(y3, 0.f);
        }
    }

    if (!GN) {
        if (v < n) {
            float val = y0 * ldf(lw, l * 4 + 0, f32) + y1 * ldf(lw, l * 4 + 1, f32)
                      + y2 * ldf(lw, l * 4 + 2, f32) + y3 * ldf(lw, l * 4 + 3, f32);
            val += __shfl_xor(val, 1, 64); val += __shfl_xor(val, 2, 64);
            val += __shfl_xor(val, 4, 64); val += __shfl_xor(val, 8, 64);
            if (l == 0) atomicAdd(&sG[batch[v]], val);
        }
        __syncthreads();
        if (t < NGRAPH && sG[t] != 0.f) atomicAdd(&gsum[t], sG[t]);
        return;
    }

    // y -> LDS (hi/lo bf16 split); zero pad rows
    {
        ushort4 h, lo;
        h.x = f2bf(y0); h.y = f2bf(y1); h.z = f2bf(y2); h.w = f2bf(y3);
        lo.x = f2bf(y0 - bf2f(h.x)); lo.y = f2bf(y1 - bf2f(h.y));
        lo.z = f2bf(y2 - bf2f(h.z)); lo.w = f2bf(y3 - bf2f(h.w));
        if (v >= n) { h = make_ushort4(0, 0, 0, 0); lo = make_ushort4(0, 0, 0, 0); }
        *(ushort4*)&sYh[grp * 72 + l * 4] = h;
        *(ushort4*)&sYl[grp * 72 + l * 4] = lo;
    }
    __syncthreads();

    // dual GEMM: 16 waves; wave ww: rows rt*16.., cols (c2, c2+4) tiles
    int ww = t >> 6, lane = t & 63;
    int m = lane & 15, q = lane >> 4;
    int rt = ww & 3, c2 = ww >> 2;
    f32x4 accW = (f32x4){0.f, 0.f, 0.f, 0.f};
    f32x4 accR = (f32x4){0.f, 0.f, 0.f, 0.f};
    int arow = rt * 16 + m;
#pragma unroll
    for (int ks = 0; ks < 2; ks++) {
        int ka = ks * 32 + q * 8;
        bf16x8 ah = *(const bf16x8*)&sYh[arow * 72 + ka];
        bf16x8 al = *(const bf16x8*)&sYl[arow * 72 + ka];
        bf16x8 bW = *(const bf16x8*)&sW[(c2 * 16 + m) * 72 + ka];
        bf16x8 bR = *(const bf16x8*)&sW[((c2 + 4) * 16 + m) * 72 + ka];
        accW = __builtin_amdgcn_mfma_f32_16x16x32_bf16(ah, bW, accW, 0, 0, 0);
        accW = __builtin_amdgcn_mfma_f32_16x16x32_bf16(al, bW, accW, 0, 0, 0);
        accR = __builtin_amdgcn_mfma_f32_16x16x32_bf16(ah, bR, accR, 0, 0, 0);
        accR = __builtin_amdgcn_mfma_f32_16x16x32_bf16(al, bR, accR, 0, 0, 0);
    }
    int col = c2 * 16 + m;
#pragma unroll
    for (int reg = 0; reg < 4; reg++) {
        int r = row0 + rt * 16 + q * 4 + reg;
        if (r < n) {
            float dv = dis[r];
            float h = accW[reg] * dv;
            hs_out[(size_t)r * 64 + col] = f2e4m3(h);
            base_out[(size_t)r * 64 + col] = h * dv + accR[reg] + bcat[col];
        }
    }
}

// ---------------- finalize ----------------
__global__ void k_final(const float* __restrict__ gsum, const int* __restrict__ gcnt,
                        const void* __restrict__ lb, const int* __restrict__ dflag,
                        void* __restrict__ out, int g) {
    int f32 = *dflag;
    int i = threadIdx.x;
    if (i < g) {
        float c = fmaxf((float)gcnt[i], 1.f);
        float v = gsum[i] / c + ldf(lb, 0, f32);
        if (f32) ((float*)out)[i] = v;
        else ((__hip_bfloat16*)out)[i] = __float2bfloat16(v);
    }
}

extern "C" void kernel_launch(void* const* d_in, const int* in_sizes, int n_in,
                              void* d_out, int out_size, void* d_ws, size_t ws_size,
                              hipStream_t stream) {
    const void* x_in = d_in[0];
    const int* edge_index = (const int*)d_in[1];
    const int* batch = (const int*)d_in[2];
    const void *W0 = d_in[3], *b0 = d_in[4], *W1 = d_in[5], *b1 = d_in[6],
               *W2 = d_in[7], *b2 = d_in[8];
    const void *RW0 = d_in[9], *rb0 = d_in[10], *RW1 = d_in[11], *rb1 = d_in[12],
               *RW2 = d_in[13], *rb2 = d_in[14];
    const void *g0 = d_in[15], *be0 = d_in[16], *g1 = d_in[17], *be1 = d_in[18],
               *g2 = d_in[19], *be2 = d_in[20], *lw = d_in[21], *lb = d_in[22];

    const int N = in_sizes[2];
    const int E = in_sizes[1] / 2;
    const int* erow = edge_index;
    const int* ecol = edge_index + E;
    const int nbuck = (N + 127) >> BSH;
    const int T = nbuck * NCH;

    // workspace carve (~50 MB)
    char* p = (char*)d_ws;
    size_t off = 0;
    float* dis = (float*)(p + off);  off = align256(off + (size_t)N * 4);
    int* offs = (int*)(p + off);     off = align256(off + (size_t)(N + 1) * 4);
    int* csr = (int*)(p + off);      off = align256(off + (size_t)E * 4);
    int* esrc = (int*)(p + off);     off = align256(off + (size_t)E * 4);
    unsigned char* et7 = (unsigned char*)(p + off); off = align256(off + (size_t)E);
    int* hist = (int*)(p + off);     off = align256(off + (size_t)T * 4);
    int* hoffs = (int*)(p + off);    off = align256(off + (size_t)(T + 1) * 4);
    unsigned char* hsA = (unsigned char*)(p + off); off = align256(off + (size_t)N * HID);
    unsigned char* hsB = (unsigned char*)(p + off); off = align256(off + (size_t)N * HID);
    float* baseA = (float*)(p + off); off = align256(off + (size_t)N * HID * 4);
    float* baseB = (float*)(p + off); off = align256(off + (size_t)N * HID * 4);
    unsigned short* wt0 = (unsigned short*)(p + off); off = align256(off + 16384 * 2);
    unsigned short* wt1 = (unsigned short*)(p + off); off = align256(off + 8192 * 2);
    unsigned short* wt2 = (unsigned short*)(p + off); off = align256(off + 8192 * 2);
    float* bcat = (float*)(p + off); off = align256(off + 192 * 4);
    int* bsum = (int*)(p + off);     off = align256(off + 256 * 4);
    int* bscan = (int*)(p + off);    off = align256(off + 256 * 4);
    float* gsum = (float*)(p + off); off = align256(off + NGRAPH * 4);
    int* gcnt = (int*)(p + off);     off = align256(off + NGRAPH * 4);
    int* dflag = (int*)(p + off);    off = align256(off + 4);
    (void)ws_size;

    const int TB = 256;
    int nbG = (N + TB - 1) / TB;
    int nbT = (T + 1023) / 1024;
    int nb_gemm = (N + 63) / 64;
    int nb_agg = (N + 63) / 64;

    k_sniff<<<1, 256, 0, stream>>>((const unsigned short*)x_in, 8192, dflag, gsum, gcnt);
    k_prep<<<nbG + 130 + NCH, TB, 0, stream>>>(batch, gcnt, N, nbG,
                                               W0, RW0, b0, rb0, W1, RW1, b1, rb1,
                                               W2, RW2, b2, rb2, dflag, wt0, wt1, wt2, bcat,
                                               ecol, E, nbuck, hist);
    k_scan1<<<nbT, TB, 0, stream>>>(hist, bsum, T);
    k_scan2<<<1, TB, 0, stream>>>(bsum, bscan, hoffs, nbT, T);
    k_scan3<<<nbT, TB, 0, stream>>>(hist, bscan, hoffs, T);
    k_scatter<<<NCH, TB, 0, stream>>>(erow, ecol, E, nbuck, hoffs, esrc, et7);
    k_bucket<<<nbuck, TB, 0, stream>>>(esrc, et7, hoffs, nbuck, N, E, offs, dis, csr);

    // layer 0 GEMM (K=128) -> hsA/baseA
    k_gemm<128, true, false><<<nb_gemm, TB, 0, stream>>>(x_in, wt0, bcat, dis, dflag, hsA, baseA, N);
    // fused agg0 + LN + GEMM1 -> hsB/baseB
    k_fagg<true><<<nb_agg, 1024, 0, stream>>>(hsA, baseA, dis, offs, csr, g0, be0, dflag, N, 1,
                                              wt1, bcat + 64, hsB, baseB, nullptr, nullptr, nullptr);
    // fused agg1 + LN + GEMM2 -> hsA/baseA
    k_fagg<true><<<nb_agg, 1024, 0, stream>>>(hsB, baseB, dis, offs, csr, g1, be1, dflag, N, 1,
                                              wt2, bcat + 128, hsA, baseA, nullptr, nullptr, nullptr);
    // agg2 + LN + readout
    k_fagg<false><<<nb_agg, 1024, 0, stream>>>(hsA, baseA, dis, offs, csr, g2, be2, dflag, N, 0,
                                               nullptr, nullptr, nullptr, nullptr, batch, lw, gsum);

    k_final<<<1, 64, 0, stream>>>(gsum, gcnt, lb, dflag, d_out, NGRAPH);
}